// Round 1
// baseline (647.325 us; speedup 1.0000x reference)
//
#include <hip/hip_runtime.h>
#include <math.h>

// Laminography forward projector, fully fused pipeline:
//  (1) centered 3D FFT of complex volume (3 generic 1D passes into d_ws)
//  (2) trilinear Fourier-slice sampling -> d_out (as float2)
//  (3) centered inverse 2D FFT, two in-place passes on d_out
// Centered transform identity (n=256, n/2 even):
//  F[k] = (-1)^k * FFT[ (-1)^x * u[x] ]   per axis, forward and inverse alike.

namespace {

template<int MODE, bool INV>
__global__ __launch_bounds__(256)
void fft_pass(const float2* in, float2* out) {
  // MODE 0: contiguous lines, base = lineIdx*256,                    stride 1
  // MODE 1: base = (lineIdx>>8)*65536 + (lineIdx&255),               stride 256
  // MODE 2: base = lineIdx,                                          stride 65536
  __shared__ float sre[8][265];   // 8 lines x 256 pts, pad 9 to dodge bank conflicts
  __shared__ float sim[8][265];
  __shared__ float twr[128];
  __shared__ float twi[128];
  const int t = threadIdx.x;
  if (t < 128) {
    const float TWO_PI = 6.28318530717958647692f;
    float ang = (INV ? TWO_PI : -TWO_PI) * ((float)t * (1.0f / 256.0f));
    float s, c;
    sincosf(ang, &s, &c);
    twr[t] = c;
    twi[t] = s;
  }
  int l, j0, base, stride;
  if (MODE == 0) { l = t >> 5; j0 = t & 31; }   // lines 256 apart: coalesce along j
  else           { l = t & 7;  j0 = t >> 3; }   // lines contiguous: coalesce along l
  const int lineIdx = (int)blockIdx.x * 8 + l;
  if (MODE == 0)      { base = lineIdx * 256;                            stride = 1;     }
  else if (MODE == 1) { base = (lineIdx >> 8) * 65536 + (lineIdx & 255); stride = 256;   }
  else                { base = lineIdx;                                  stride = 65536; }

  // load with (-1)^x pre-twiddle (centering)
  #pragma unroll
  for (int r = 0; r < 8; r++) {
    int j = j0 + 32 * r;
    float2 v = in[base + j * stride];
    float sgn = (j & 1) ? -1.0f : 1.0f;
    sre[l][j] = v.x * sgn;
    sim[l][j] = v.y * sgn;
  }
  __syncthreads();

  // radix-2 DIF, 8 stages; 32 threads per line, 4 butterflies/thread/stage
  const int line = t >> 5;
  const int lane = t & 31;
  #pragma unroll
  for (int s = 0; s < 8; s++) {
    const int half = 128 >> s;
    #pragma unroll
    for (int r = 0; r < 4; r++) {
      int b   = lane + 32 * r;
      int pos = b & (half - 1);
      int grp = b >> (7 - s);
      int i   = (grp << (8 - s)) + pos;
      int j   = i + half;
      float ar = sre[line][i], ai = sim[line][i];
      float br = sre[line][j], bi = sim[line][j];
      sre[line][i] = ar + br;
      sim[line][i] = ai + bi;
      float dr = ar - br, di = ai - bi;
      int mm = pos << s;                 // twiddle exponent, always < 128
      float wr = twr[mm], wi = twi[mm];
      sre[line][j] = dr * wr - di * wi;
      sim[line][j] = dr * wi + di * wr;
    }
    __syncthreads();
  }

  // store: DIF leaves X[bitrev(p)] at p; apply (-1)^k post-twiddle (+ 1/n for inverse)
  const float scale = INV ? (1.0f / 256.0f) : 1.0f;
  #pragma unroll
  for (int r = 0; r < 8; r++) {
    int j = j0 + 32 * r;
    int rev = (int)(__brev((unsigned)j) >> 24);
    float sgn = (j & 1) ? -scale : scale;
    float2 v;
    v.x = sre[l][rev] * sgn;
    v.y = sim[l][rev] * sgn;
    out[base + j * stride] = v;
  }
}

__global__ __launch_bounds__(256)
void sample_kernel(const float2* __restrict__ F, float2* __restrict__ out,
                   const float* __restrict__ theta, const float* __restrict__ tiltp) {
  const int m = blockIdx.z;
  const int b = blockIdx.x * 16 + threadIdx.x;   // detector fast axis (ku)
  const int a = blockIdx.y * 16 + threadIdx.y;   // detector slow axis (kv)
  float th = theta[m];
  float ct = cosf(th), st = sinf(th);
  float tl = tiltp[0];
  float cp = cosf(tl), sp = sinf(tl);
  float bu = (float)(b - 128);
  float av = (float)(a - 128);
  // pos = bu*e_u + av*e_v + 128, e_u=(ct,st,0), e_v=(-st*cp, ct*cp, sp)
  float p0 = bu * ct + av * (-st * cp) + 128.0f;
  float p1 = bu * st + av * (ct * cp) + 128.0f;
  float p2 = av * sp + 128.0f;
  float f0 = floorf(p0), f1 = floorf(p1), f2 = floorf(p2);
  int x0 = (int)f0, y0 = (int)f1, z0 = (int)f2;
  float fx = p0 - f0, fy = p1 - f1, fz = p2 - f2;
  float accr = 0.0f, acci = 0.0f;
  #pragma unroll
  for (int dx = 0; dx < 2; dx++) {
    int x = x0 + dx;
    bool vx = (x >= 0) && (x < 256);
    int xc = min(max(x, 0), 255);
    float wx = dx ? fx : (1.0f - fx);
    #pragma unroll
    for (int dy = 0; dy < 2; dy++) {
      int y = y0 + dy;
      bool vy = vx && (y >= 0) && (y < 256);
      int yc = min(max(y, 0), 255);
      float wxy = wx * (dy ? fy : (1.0f - fy));
      int rowbase = (xc * 256 + yc) * 256;
      #pragma unroll
      for (int dz = 0; dz < 2; dz++) {
        int z = z0 + dz;
        bool v = vy && (z >= 0) && (z < 256);
        int zc = min(max(z, 0), 255);
        float w = v ? wxy * (dz ? fz : (1.0f - fz)) : 0.0f;
        float2 c = F[rowbase + zc];   // clamped gather; masked by w
        accr += w * c.x;
        acci += w * c.y;
      }
    }
  }
  out[(m * 256 + a) * 256 + b] = make_float2(accr, acci);
}

}  // namespace

extern "C" void kernel_launch(void* const* d_in, const int* in_sizes, int n_in,
                              void* d_out, int out_size, void* d_ws, size_t ws_size,
                              hipStream_t stream) {
  const float2* w  = (const float2*)d_in[0];   // (256,256,256,2) f32 == float2 complex
  const float*  th = (const float*)d_in[1];    // (180,)
  const float*  tl = (const float*)d_in[2];    // scalar
  float2* F    = (float2*)d_ws;                // 256^3 complex64 = 128 MiB
  float2* out2 = (float2*)d_out;               // (180,256,256) complex64 view of output

  // forward 3D FFT (centered), one pass per axis, 65536 lines each
  fft_pass<0, false><<<8192, 256, 0, stream>>>(w, F);   // axis 2 (contiguous)
  fft_pass<1, false><<<8192, 256, 0, stream>>>(F, F);   // axis 1 (stride 256)
  fft_pass<2, false><<<8192, 256, 0, stream>>>(F, F);   // axis 0 (stride 65536)

  // Fourier-slice trilinear sampling -> d_out
  dim3 g(16, 16, 180), blk(16, 16);
  sample_kernel<<<g, blk, 0, stream>>>(F, out2, th, tl);

  // centered inverse 2D FFT per angle, in place in d_out; 180*256 lines per pass
  fft_pass<0, true><<<5760, 256, 0, stream>>>(out2, out2);  // axis b (contiguous)
  fft_pass<1, true><<<5760, 256, 0, stream>>>(out2, out2);  // axis a (stride 256)
}